// Round 4
// baseline (101.951 us; speedup 1.0000x reference)
//
#include <hip/hip_runtime.h>

// Two-phase: (1) build_w: push 256 basis states through the deferred-CNOT
// register simulator (validated R1-R3) -> circuit matrix W (bf16, [n][k]:
// n=0..255 Re(stored amp i), n=256..511 Im; k = input basis j).
// (2) gemm_z: E (B x 256 real product-state encoding, bf16) times W^T via
// MFMA 16x16x32; epilogue squares, applies the 8 stored-space sign masks
// {0x80,0x40,0x20,0x10,0x88,0x44,0x22,0x11} and reduces.

#define NGATES 32
typedef short s8v __attribute__((ext_vector_type(8)));   // 8 bf16 (4 VGPRs)
typedef float f4v __attribute__((ext_vector_type(4)));

__device__ __forceinline__ unsigned short f2bf(float f) {
    unsigned u = __float_as_uint(f);
    u += 0x7FFFu + ((u >> 16) & 1u);
    return (unsigned short)(u >> 16);
}
__device__ __forceinline__ float xsgn(float f, unsigned m) {
    return __int_as_float(__float_as_int(f) ^ (int)m);
}
template<int M>
__device__ __forceinline__ float shx(float v) {
    return __int_as_float(__builtin_amdgcn_ds_swizzle(__float_as_int(v), (M << 10) | 0x1F));
}

// ---- deferred-CNOT gate masks (validated R1-R3) ----
constexpr bool selon(int l, int d) {
    return (l == 0) ? (d == 0) : (((d + l - 1) & (l - 1)) == (l - 1));
}
constexpr int lm_of(int l, int q) {
    int m = 0;
    for (int d = 0; q + d <= 7; ++d)
        if ((l & d) == d) { int qq = q + d; if (qq <= 3) m |= 1 << (3 - qq); }
    return m;
}
constexpr int rm_of(int l, int q) {
    int m = 0;
    for (int d = 0; q + d <= 7; ++d)
        if ((l & d) == d) { int qq = q + d; if (qq >= 4) m |= 1 << (7 - qq); }
    return m;
}
constexpr int slm_of(int l, int q) {
    int m = 0;
    for (int d = 0; d <= q; ++d)
        if (selon(l, d)) { int k = q - d; if (k <= 3) m |= 1 << (3 - k); }
    return m;
}
constexpr int srm_of(int l, int q) {
    int m = 0;
    for (int d = 0; d <= q; ++d)
        if (selon(l, d)) { int k = q - d; if (k >= 4) m |= 1 << (7 - k); }
    return m;
}

template<int LM, int RM, int SLM, int SRM>
__device__ __forceinline__ void apply_gate(float ar[16], float ai[16], int lane,
                                           const float4 g)
{
    unsigned sm = 0;
    if constexpr (SLM != 0)
        sm = (unsigned)((__builtin_popcount(lane & SLM) & 1) << 31);
    const float c0r = g.x, c1i = g.w;
    const float c0i0 = xsgn(g.y, sm);
    const float c1r0 = xsgn(g.z, sm);
    const float c0i1 = xsgn(g.y, sm ^ 0x80000000u);
    const float c1r1 = xsgn(g.z, sm ^ 0x80000000u);

    if constexpr (RM == 0) {
        #pragma unroll
        for (int r = 0; r < 16; ++r) {
            const bool c1 = (__builtin_popcount(r & SRM) & 1) != 0;
            const float c0i = c1 ? c0i1 : c0i0;
            const float c1r = c1 ? c1r1 : c1r0;
            const float br = shx<LM>(ar[r]);
            const float bi = shx<LM>(ai[r]);
            const float nr = c0r*ar[r] - c0i*ai[r] + c1r*br - c1i*bi;
            const float ni = c0r*ai[r] + c0i*ar[r] + c1r*bi + c1i*br;
            ar[r] = nr; ai[r] = ni;
        }
    } else {
        #pragma unroll
        for (int r = 0; r < 16; ++r) {
            const int p = r ^ RM;
            if (p < r) continue;
            float br_r, bi_r, br_p, bi_p;
            if constexpr (LM != 0) {
                br_r = shx<LM>(ar[p]); bi_r = shx<LM>(ai[p]);
                br_p = shx<LM>(ar[r]); bi_p = shx<LM>(ai[r]);
            } else {
                br_r = ar[p]; bi_r = ai[p];
                br_p = ar[r]; bi_p = ai[r];
            }
            const bool cr = (__builtin_popcount(r & SRM) & 1) != 0;
            const bool cp = (__builtin_popcount(p & SRM) & 1) != 0;
            const float c0i_r = cr ? c0i1 : c0i0, c1r_r = cr ? c1r1 : c1r0;
            const float c0i_p = cp ? c0i1 : c0i0, c1r_p = cp ? c1r1 : c1r0;
            const float nr_r = c0r*ar[r] - c0i_r*ai[r] + c1r_r*br_r - c1i*bi_r;
            const float ni_r = c0r*ai[r] + c0i_r*ar[r] + c1r_r*bi_r + c1i*br_r;
            const float nr_p = c0r*ar[p] - c0i_p*ai[p] + c1r_p*br_p - c1i*bi_p;
            const float ni_p = c0r*ai[p] + c0i_p*ar[p] + c1r_p*bi_p + c1i*br_p;
            ar[r] = nr_r; ai[r] = ni_r;
            ar[p] = nr_p; ai[p] = ni_p;
        }
    }
}

#define GATE(L, Q) apply_gate<lm_of(L,Q), rm_of(L,Q), slm_of(L,Q), srm_of(L,Q)>( \
                       ar, ai, lane, gsh4[(L)*8+(Q)])
#define LAYER(L) GATE(L,0); GATE(L,1); GATE(L,2); GATE(L,3); \
                 GATE(L,4); GATE(L,5); GATE(L,6); GATE(L,7);

// ---- kernel 1: build circuit matrix (16 blocks x 256 thr; 16 basis/block) ----
__global__ __launch_bounds__(256) void build_w(const float* __restrict__ w,
                                               unsigned short* __restrict__ W)
{
    __shared__ float4 gsh4[NGATES];
    const int tid = threadIdx.x;
    if (tid < NGATES) {
        float hx = 0.5f * w[tid*3+0];
        float hy = 0.5f * w[tid*3+1];
        float hz = 0.5f * w[tid*3+2];
        float cx = cosf(hx), sx = sinf(hx);
        float cy = cosf(hy), sy = sinf(hy);
        float cz = cosf(hz), sz = sinf(hz);
        float m00r = cy*cx,  m00i =  sy*sx;
        float m01r = -sy*cx, m01i = -cy*sx;
        gsh4[tid] = make_float4(cz*m00r + sz*m00i,
                                cz*m00i - sz*m00r,
                                cz*m01r + sz*m01i,
                                cz*m01i - sz*m01r);
    }
    __syncthreads();

    const int lane = tid & 63;
    const int il   = lane & 15;
    const int j    = blockIdx.x * 16 + (tid >> 4);   // basis state (true index)

    float ar[16], ai[16];
    #pragma unroll
    for (int r = 0; r < 16; ++r) {
        ar[r] = (((j >> 4) == il) && ((j & 15) == r)) ? 1.f : 0.f;
        ai[r] = 0.f;
    }
    LAYER(0)
    LAYER(1)
    LAYER(2)
    LAYER(3)
    #pragma unroll
    for (int r = 0; r < 16; ++r) {
        const int i = (il << 4) | r;                 // stored amp index
        W[i * 256 + j]         = f2bf(ar[r]);
        W[(256 + i) * 256 + j] = f2bf(ai[r]);
    }
}

// ---- kernel 2: E x W^T GEMM + squared-signed-sum epilogue ----
// block = 16 samples (M=16); 4 waves split N: wave g -> cols i in [64g,64g+64)
// for both Re (n=i) and Im (n=256+i). K=256, 8 MFMA ksteps.
__global__ __launch_bounds__(256, 4) void gemm_z(const float* __restrict__ x,
                                                 const unsigned short* __restrict__ W,
                                                 float* __restrict__ out, int B)
{
    __shared__ __align__(16) unsigned short El[16 * 264];  // [m][k], k padded +8
    __shared__ float zbuf[4][16][8];

    const int tid = threadIdx.x;
    const int Mbase = blockIdx.x * 16;

    // ---- encode 16 samples into LDS (bf16) ----
    {
        const int s  = tid >> 4;        // sample row 0..15
        const int tk = tid & 15;        // k bits 7..4
        const float4* xp = (const float4*)(x + (Mbase + s) * 8);
        float4 xa = xp[0], xb = xp[1];
        float xs8[8] = {xa.x, xa.y, xa.z, xa.w, xb.x, xb.y, xb.z, xb.w};
        float c[8], sn[8];
        #pragma unroll
        for (int q = 0; q < 8; ++q) __sincosf(0.5f * xs8[q], &sn[q], &c[q]);
        float base = ((tk & 8) ? sn[0] : c[0]) * ((tk & 4) ? sn[1] : c[1])
                   * ((tk & 2) ? sn[2] : c[2]) * ((tk & 1) ? sn[3] : c[3]);
        float P45[4] = {c[4]*c[5], c[4]*sn[5], sn[4]*c[5], sn[4]*sn[5]};
        float P67[4] = {c[6]*c[7], c[6]*sn[7], sn[6]*c[7], sn[6]*sn[7]};
        unsigned short* dst = &El[s * 264 + tk * 16];
        #pragma unroll
        for (int v = 0; v < 16; ++v)
            dst[v] = f2bf(base * P45[v >> 2] * P67[v & 3]);
    }
    __syncthreads();

    const int lane = tid & 63;
    const int g    = tid >> 6;          // wave id = col-group (i bits 7:6)
    const int col  = lane & 15;
    const int quad = lane >> 4;

    f4v accR[4], accI[4];
    #pragma unroll
    for (int nt = 0; nt < 4; ++nt) {
        accR[nt] = (f4v){0.f, 0.f, 0.f, 0.f};
        accI[nt] = (f4v){0.f, 0.f, 0.f, 0.f};
    }

    const s8v* Wp = (const s8v*)W;
    const s8v* Ap = (const s8v*)El;     // row stride 33 units of 16B

    #pragma unroll
    for (int ks = 0; ks < 8; ++ks) {
        const s8v a = Ap[col * 33 + ks * 4 + quad];   // A[m=col][k]
        #pragma unroll
        for (int nt = 0; nt < 4; ++nt) {
            const int nR = g * 64 + nt * 16 + col;    // B[n][k], n = stored i
            const s8v bR = Wp[nR * 32 + ks * 4 + quad];
            accR[nt] = __builtin_amdgcn_mfma_f32_16x16x32_bf16(a, bR, accR[nt], 0, 0, 0);
            const s8v bI = Wp[(nR + 256) * 32 + ks * 4 + quad];
            accI[nt] = __builtin_amdgcn_mfma_f32_16x16x32_bf16(a, bI, accI[nt], 0, 0, 0);
        }
    }

    // ---- epilogue: p = re^2+im^2; S0=sum, S1=(-1)^{nt1}, S2=(-1)^{nt0} ----
    float S0[4], S1[4], S2[4];
    #pragma unroll
    for (int reg = 0; reg < 4; ++reg) {
        float p0 = accR[0][reg]*accR[0][reg] + accI[0][reg]*accI[0][reg];
        float p1 = accR[1][reg]*accR[1][reg] + accI[1][reg]*accI[1][reg];
        float p2 = accR[2][reg]*accR[2][reg] + accI[2][reg]*accI[2][reg];
        float p3 = accR[3][reg]*accR[3][reg] + accI[3][reg]*accI[3][reg];
        S0[reg] = (p0 + p1) + (p2 + p3);
        S1[reg] = (p0 + p1) - (p2 + p3);
        S2[reg] = (p0 - p1) + (p2 - p3);
    }

    // 4-stage WHT over col for each stream: lane col=m holds freq-m coeff
    const unsigned b1 = (unsigned)(col & 1) << 31;
    const unsigned b2 = (unsigned)(col & 2) << 30;
    const unsigned b4 = (unsigned)(col & 4) << 29;
    const unsigned b8 = (unsigned)(col & 8) << 28;
    #pragma unroll
    for (int reg = 0; reg < 4; ++reg) {
        float v;
        v = S0[reg];
        { float t = shx<1>(v); v = t + xsgn(v, b1); }
        { float t = shx<2>(v); v = t + xsgn(v, b2); }
        { float t = shx<4>(v); v = t + xsgn(v, b4); }
        { float t = shx<8>(v); v = t + xsgn(v, b8); }
        S0[reg] = v;
        v = S1[reg];
        { float t = shx<1>(v); v = t + xsgn(v, b1); }
        { float t = shx<2>(v); v = t + xsgn(v, b2); }
        { float t = shx<4>(v); v = t + xsgn(v, b4); }
        { float t = shx<8>(v); v = t + xsgn(v, b8); }
        S1[reg] = v;
        v = S2[reg];
        { float t = shx<1>(v); v = t + xsgn(v, b1); }
        { float t = shx<2>(v); v = t + xsgn(v, b2); }
        { float t = shx<4>(v); v = t + xsgn(v, b4); }
        { float t = shx<8>(v); v = t + xsgn(v, b8); }
        S2[reg] = v;
    }

    // sign masks: q0:0x80(g1) q1:0x40(g0) q2:0x20(nt1->S1) q3:0x10(nt0->S2)
    //             q4:0x88(g1^col3) q5:0x44(g0^col2) q6:0x22(nt1^col1) q7:0x11(nt0^col0)
    const unsigned sgG1 = (unsigned)(g & 2) << 30;
    const unsigned sgG0 = (unsigned)(g & 1) << 31;
    if (col == 0) {
        #pragma unroll
        for (int reg = 0; reg < 4; ++reg) {
            const int row = quad * 4 + reg;
            zbuf[g][row][0] = xsgn(S0[reg], sgG1);
            zbuf[g][row][1] = xsgn(S0[reg], sgG0);
            zbuf[g][row][2] = S1[reg];
            zbuf[g][row][3] = S2[reg];
        }
    } else if (col == 8) {
        #pragma unroll
        for (int reg = 0; reg < 4; ++reg)
            zbuf[g][quad * 4 + reg][4] = xsgn(S0[reg], sgG1);
    } else if (col == 4) {
        #pragma unroll
        for (int reg = 0; reg < 4; ++reg)
            zbuf[g][quad * 4 + reg][5] = xsgn(S0[reg], sgG0);
    } else if (col == 2) {
        #pragma unroll
        for (int reg = 0; reg < 4; ++reg)
            zbuf[g][quad * 4 + reg][6] = S1[reg];
    } else if (col == 1) {
        #pragma unroll
        for (int reg = 0; reg < 4; ++reg)
            zbuf[g][quad * 4 + reg][7] = S2[reg];
    }
    __syncthreads();

    if (tid < 128) {
        const int row = tid >> 3, q = tid & 7;
        out[(Mbase + row) * 8 + q] = (zbuf[0][row][q] + zbuf[1][row][q])
                                   + (zbuf[2][row][q] + zbuf[3][row][q]);
    }
}

extern "C" void kernel_launch(void* const* d_in, const int* in_sizes, int n_in,
                              void* d_out, int out_size, void* d_ws, size_t ws_size,
                              hipStream_t stream) {
    const float* x = (const float*)d_in[0];
    const float* w = (const float*)d_in[1];
    float* out = (float*)d_out;
    unsigned short* W = (unsigned short*)d_ws;   // 512 x 256 bf16 = 256 KB
    const int B = in_sizes[0] / 8;               // 16384 samples
    build_w<<<16, 256, 0, stream>>>(w, W);
    gemm_z<<<B / 16, 256, 0, stream>>>(x, W, out, B);
}

// Round 6
// 91.250 us; speedup vs baseline: 1.1173x; 1.1173x over previous
//
#include <hip/hip_runtime.h>

// Phase 1 (build_w): push 256 basis states through the deferred-CNOT forward
// simulator (validated R1-R4) -> W (bf16) [n][k]: n=0..255 Re(stored amp i),
// n=256..511 Im; k = input basis j.  STORED-index space throughout.
// Phase 2 (gemm_z): C = E x W^T via MFMA 16x16x32 bf16, M=32 per block;
// epilogue squares and reduces with stored-space sign masks
// {0x80,0x40,0x20,0x10,0x88,0x44,0x22,0x11} (validated R4).

#define NGATES 32
typedef short s8v __attribute__((ext_vector_type(8)));   // 8 bf16 = 16 B
typedef float f4v __attribute__((ext_vector_type(4)));

__device__ __forceinline__ unsigned short f2bf(float f) {
    unsigned u = __float_as_uint(f);
    u += 0x7FFFu + ((u >> 16) & 1u);
    return (unsigned short)(u >> 16);
}
__device__ __forceinline__ float xsgn(float f, unsigned m) {
    return __int_as_float(__float_as_int(f) ^ (int)m);
}
template<int M>
__device__ __forceinline__ float shx(float v) {
    return __int_as_float(__builtin_amdgcn_ds_swizzle(__float_as_int(v), (M << 10) | 0x1F));
}

// ---- deferred-CNOT gate masks, FORWARD circuit (validated R1-R4) ----
constexpr bool selon(int l, int d) {
    return (l == 0) ? (d == 0) : (((d + l - 1) & (l - 1)) == (l - 1));
}
constexpr int lm_of(int l, int q) {
    int m = 0;
    for (int d = 0; q + d <= 7; ++d)
        if ((l & d) == d) { int qq = q + d; if (qq <= 3) m |= 1 << (3 - qq); }
    return m;
}
constexpr int rm_of(int l, int q) {
    int m = 0;
    for (int d = 0; q + d <= 7; ++d)
        if ((l & d) == d) { int qq = q + d; if (qq >= 4) m |= 1 << (7 - qq); }
    return m;
}
constexpr int slm_of(int l, int q) {
    int m = 0;
    for (int d = 0; d <= q; ++d)
        if (selon(l, d)) { int k = q - d; if (k <= 3) m |= 1 << (3 - k); }
    return m;
}
constexpr int srm_of(int l, int q) {
    int m = 0;
    for (int d = 0; d <= q; ++d)
        if (selon(l, d)) { int k = q - d; if (k >= 4) m |= 1 << (7 - k); }
    return m;
}

template<int LM, int RM, int SLM, int SRM>
__device__ __forceinline__ void apply_gate(float ar[16], float ai[16], int lane,
                                           const float4 g)  // u00r,u00i,u01r,u01i
{
    unsigned sm = 0;
    if constexpr (SLM != 0)
        sm = (unsigned)((__builtin_popcount(lane & SLM) & 1) << 31);
    const float c0r = g.x, c1i = g.w;
    const float c0i0 = xsgn(g.y, sm);
    const float c1r0 = xsgn(g.z, sm);
    const float c0i1 = xsgn(g.y, sm ^ 0x80000000u);
    const float c1r1 = xsgn(g.z, sm ^ 0x80000000u);

    if constexpr (RM == 0) {
        #pragma unroll
        for (int r = 0; r < 16; ++r) {
            const bool c1 = (__builtin_popcount(r & SRM) & 1) != 0;
            const float c0i = c1 ? c0i1 : c0i0;
            const float c1r = c1 ? c1r1 : c1r0;
            const float br = shx<LM>(ar[r]);
            const float bi = shx<LM>(ai[r]);
            const float nr = c0r*ar[r] - c0i*ai[r] + c1r*br - c1i*bi;
            const float ni = c0r*ai[r] + c0i*ar[r] + c1r*bi + c1i*br;
            ar[r] = nr; ai[r] = ni;
        }
    } else {
        #pragma unroll
        for (int r = 0; r < 16; ++r) {
            const int p = r ^ RM;
            if (p < r) continue;
            float br_r, bi_r, br_p, bi_p;
            if constexpr (LM != 0) {
                br_r = shx<LM>(ar[p]); bi_r = shx<LM>(ai[p]);
                br_p = shx<LM>(ar[r]); bi_p = shx<LM>(ai[r]);
            } else {
                br_r = ar[p]; bi_r = ai[p];
                br_p = ar[r]; bi_p = ai[r];
            }
            const bool cr = (__builtin_popcount(r & SRM) & 1) != 0;
            const bool cp = (__builtin_popcount(p & SRM) & 1) != 0;
            const float c0i_r = cr ? c0i1 : c0i0, c1r_r = cr ? c1r1 : c1r0;
            const float c0i_p = cp ? c0i1 : c0i0, c1r_p = cp ? c1r1 : c1r0;
            const float nr_r = c0r*ar[r] - c0i_r*ai[r] + c1r_r*br_r - c1i*bi_r;
            const float ni_r = c0r*ai[r] + c0i_r*ar[r] + c1r_r*bi_r + c1i*br_r;
            const float nr_p = c0r*ar[p] - c0i_p*ai[p] + c1r_p*br_p - c1i*bi_p;
            const float ni_p = c0r*ai[p] + c0i_p*ar[p] + c1r_p*bi_p + c1i*br_p;
            ar[r] = nr_r; ai[r] = ni_r;
            ar[p] = nr_p; ai[p] = ni_p;
        }
    }
}

#define GATE(L, Q) apply_gate<lm_of(L,Q), rm_of(L,Q), slm_of(L,Q), srm_of(L,Q)>( \
                       ar, ai, lane, gsh4[(L)*8+(Q)])
#define LAYER(L) GATE(L,0); GATE(L,1); GATE(L,2); GATE(L,3); \
                 GATE(L,4); GATE(L,5); GATE(L,6); GATE(L,7);

// ---- kernel 1: build circuit matrix (16 blocks x 256 thr; 16 basis/block) ----
__global__ __launch_bounds__(256) void build_w(const float* __restrict__ w,
                                               unsigned short* __restrict__ W)
{
    __shared__ float4 gsh4[NGATES];
    const int tid = threadIdx.x;
    if (tid < NGATES) {
        float hx = 0.5f * w[tid*3+0];
        float hy = 0.5f * w[tid*3+1];
        float hz = 0.5f * w[tid*3+2];
        float cx = cosf(hx), sx = sinf(hx);
        float cy = cosf(hy), sy = sinf(hy);
        float cz = cosf(hz), sz = sinf(hz);
        float m00r = cy*cx,  m00i =  sy*sx;
        float m01r = -sy*cx, m01i = -cy*sx;
        gsh4[tid] = make_float4(cz*m00r + sz*m00i,
                                cz*m00i - sz*m00r,
                                cz*m01r + sz*m01i,
                                cz*m01i - sz*m01r);
    }
    __syncthreads();

    const int lane = tid & 63;
    const int il   = lane & 15;
    const int j    = blockIdx.x * 16 + (tid >> 4);   // basis state (true index)

    float ar[16], ai[16];
    #pragma unroll
    for (int r = 0; r < 16; ++r) {
        ar[r] = (((j >> 4) == il) && ((j & 15) == r)) ? 1.f : 0.f;
        ai[r] = 0.f;
    }
    LAYER(0)
    LAYER(1)
    LAYER(2)
    LAYER(3)
    #pragma unroll
    for (int r = 0; r < 16; ++r) {
        const int i = (il << 4) | r;                 // stored amp index
        W[i * 256 + j]         = f2bf(ar[r]);
        W[(256 + i) * 256 + j] = f2bf(ai[r]);
    }
}

// ---- kernel 2: E x W^T GEMM + signed-square epilogue; M=32 per block ----
__global__ __launch_bounds__(256, 2) void gemm_z(const float* __restrict__ x,
                                                 const unsigned short* __restrict__ W,
                                                 float* __restrict__ out, int B)
{
    __shared__ __align__(16) unsigned short El[32 * 264];  // [m][k], k padded +8
    __shared__ float zbuf[4][32][8];

    const int tid = threadIdx.x;
    const int Mbase = blockIdx.x * 32;

    // ---- encode 32 samples into LDS (bf16) ----
    #pragma unroll
    for (int ss = 0; ss < 2; ++ss) {
        const int s  = (tid >> 4) + 16 * ss;
        const int tk = tid & 15;
        const float4* xp = (const float4*)(x + (size_t)(Mbase + s) * 8);
        float4 xa = xp[0], xb = xp[1];
        float xs8[8] = {xa.x, xa.y, xa.z, xa.w, xb.x, xb.y, xb.z, xb.w};
        float c[8], sn[8];
        #pragma unroll
        for (int q = 0; q < 8; ++q) __sincosf(0.5f * xs8[q], &sn[q], &c[q]);
        float base = ((tk & 8) ? sn[0] : c[0]) * ((tk & 4) ? sn[1] : c[1])
                   * ((tk & 2) ? sn[2] : c[2]) * ((tk & 1) ? sn[3] : c[3]);
        float P45[4] = {c[4]*c[5], c[4]*sn[5], sn[4]*c[5], sn[4]*sn[5]};
        float P67[4] = {c[6]*c[7], c[6]*sn[7], sn[6]*c[7], sn[6]*sn[7]};
        unsigned short* dst = &El[s * 264 + tk * 16];
        #pragma unroll
        for (int v = 0; v < 16; ++v)
            dst[v] = f2bf(base * P45[v >> 2] * P67[v & 3]);
    }
    __syncthreads();

    const int lane = tid & 63;
    const int g    = tid >> 6;          // wave id = col-group (stored i bits 7:6)
    const int col  = lane & 15;
    const int quad = lane >> 4;

    f4v accR[2][4], accI[2][4];         // [mtile][nt]
    #pragma unroll
    for (int mt = 0; mt < 2; ++mt)
        #pragma unroll
        for (int nt = 0; nt < 4; ++nt) {
            accR[mt][nt] = (f4v){0.f, 0.f, 0.f, 0.f};
            accI[mt][nt] = (f4v){0.f, 0.f, 0.f, 0.f};
        }

    const s8v* Wp = (const s8v*)W;
    const s8v* Ap = (const s8v*)El;     // row stride 33 (16B units)

    #pragma unroll
    for (int ks = 0; ks < 8; ++ks) {
        const s8v a0 = Ap[col * 33 + ks * 4 + quad];
        const s8v a1 = Ap[(16 + col) * 33 + ks * 4 + quad];
        #pragma unroll
        for (int nt = 0; nt < 4; ++nt) {
            const int nR = g * 64 + nt * 16 + col;    // stored index i
            const s8v bR = Wp[nR * 32 + ks * 4 + quad];
            const s8v bI = Wp[(nR + 256) * 32 + ks * 4 + quad];
            accR[0][nt] = __builtin_amdgcn_mfma_f32_16x16x32_bf16(a0, bR, accR[0][nt], 0, 0, 0);
            accR[1][nt] = __builtin_amdgcn_mfma_f32_16x16x32_bf16(a1, bR, accR[1][nt], 0, 0, 0);
            accI[0][nt] = __builtin_amdgcn_mfma_f32_16x16x32_bf16(a0, bI, accI[0][nt], 0, 0, 0);
            accI[1][nt] = __builtin_amdgcn_mfma_f32_16x16x32_bf16(a1, bI, accI[1][nt], 0, 0, 0);
        }
    }

    // ---- epilogue (stored-index signs, validated R4) ----
    const unsigned b1 = (unsigned)(col & 1) << 31;
    const unsigned b2 = (unsigned)(col & 2) << 30;
    const unsigned b4 = (unsigned)(col & 4) << 29;
    const unsigned b8 = (unsigned)(col & 8) << 28;
    const unsigned gm1 = (unsigned)(g & 2) << 30;
    const unsigned gm0 = (unsigned)(g & 1) << 31;

    #pragma unroll
    for (int mt = 0; mt < 2; ++mt) {
        float S0[4], S1[4], S2[4];
        #pragma unroll
        for (int reg = 0; reg < 4; ++reg) {
            float p0 = accR[mt][0][reg]*accR[mt][0][reg] + accI[mt][0][reg]*accI[mt][0][reg];
            float p1 = accR[mt][1][reg]*accR[mt][1][reg] + accI[mt][1][reg]*accI[mt][1][reg];
            float p2 = accR[mt][2][reg]*accR[mt][2][reg] + accI[mt][2][reg]*accI[mt][2][reg];
            float p3 = accR[mt][3][reg]*accR[mt][3][reg] + accI[mt][3][reg]*accI[mt][3][reg];
            S0[reg] = (p0 + p1) + (p2 + p3);
            S1[reg] = (p0 + p1) - (p2 + p3);   // q2 sign: nt bit1
            S2[reg] = (p0 - p1) + (p2 - p3);   // q3 sign: nt bit0
        }
        #pragma unroll
        for (int reg = 0; reg < 4; ++reg) {
            float v = S0[reg];
            { float t = shx<1>(v); v = t + xsgn(v, b1); }
            { float t = shx<2>(v); v = t + xsgn(v, b2); }
            { float t = shx<4>(v); v = t + xsgn(v, b4); }
            { float t = shx<8>(v); v = t + xsgn(v, b8); }
            S0[reg] = v;
            float u = S1[reg];
            { float t = shx<1>(u); u = t + xsgn(u, b1); }
            { float t = shx<2>(u); u = t + xsgn(u, b2); }
            { float t = shx<4>(u); u = t + xsgn(u, b4); }
            { float t = shx<8>(u); u = t + xsgn(u, b8); }
            S1[reg] = u;
            float t2 = S2[reg];
            { float t = shx<1>(t2); t2 = t + xsgn(t2, b1); }
            { float t = shx<2>(t2); t2 = t + xsgn(t2, b2); }
            { float t = shx<4>(t2); t2 = t + xsgn(t2, b4); }
            { float t = shx<8>(t2); t2 = t + xsgn(t2, b8); }
            S2[reg] = t2;
        }
        // masks: q0:0x80(g1) q1:0x40(g0) q2:0x20->S1 q3:0x10->S2
        //        q4:0x88(g1,WHT lane8) q5:0x44(g0,lane4) q6:0x22(S1,lane2) q7:0x11(S2,lane1)
        #pragma unroll
        for (int reg = 0; reg < 4; ++reg) {
            const int row = mt * 16 + quad * 4 + reg;
            if (col == 0) {
                zbuf[g][row][0] = xsgn(S0[reg], gm1);
                zbuf[g][row][1] = xsgn(S0[reg], gm0);
                zbuf[g][row][2] = S1[reg];
                zbuf[g][row][3] = S2[reg];
            } else if (col == 8) {
                zbuf[g][row][4] = xsgn(S0[reg], gm1);
            } else if (col == 4) {
                zbuf[g][row][5] = xsgn(S0[reg], gm0);
            } else if (col == 2) {
                zbuf[g][row][6] = S1[reg];
            } else if (col == 1) {
                zbuf[g][row][7] = S2[reg];
            }
        }
    }
    __syncthreads();

    {
        const int row = tid >> 3, q = tid & 7;
        out[(size_t)(Mbase + row) * 8 + q] = (zbuf[0][row][q] + zbuf[1][row][q])
                                           + (zbuf[2][row][q] + zbuf[3][row][q]);
    }
}

extern "C" void kernel_launch(void* const* d_in, const int* in_sizes, int n_in,
                              void* d_out, int out_size, void* d_ws, size_t ws_size,
                              hipStream_t stream) {
    const float* x = (const float*)d_in[0];
    const float* w = (const float*)d_in[1];
    float* out = (float*)d_out;
    unsigned short* W = (unsigned short*)d_ws;   // 512 x 256 bf16 = 256 KB
    const int B = in_sizes[0] / 8;               // 16384 samples
    build_w<<<16, 256, 0, stream>>>(w, W);
    gemm_z<<<B / 32, 256, 0, stream>>>(x, W, out, B);
}

// Round 7
// 89.733 us; speedup vs baseline: 1.1362x; 1.0169x over previous
//
#include <hip/hip_runtime.h>

// Phase 1 (build_w): push 256 basis states through the deferred-CNOT forward
// simulator (validated R1-R5) -> W (bf16) [n][k]: n=0..255 Re(stored amp i),
// n=256..511 Im; k = input basis j.  STORED-index space throughout.
// Phase 2 (gemm_z): C = E x W^T via MFMA 16x16x32 bf16, M=32 per block;
// K-loop is a 2-stage register software pipeline (no full unroll -> no spill).
// Epilogue squares and reduces with stored-space sign masks (validated R4/R5).

#define NGATES 32
typedef short s8v __attribute__((ext_vector_type(8)));   // 8 bf16 = 16 B
typedef float f4v __attribute__((ext_vector_type(4)));

__device__ __forceinline__ unsigned short f2bf(float f) {
    unsigned u = __float_as_uint(f);
    u += 0x7FFFu + ((u >> 16) & 1u);
    return (unsigned short)(u >> 16);
}
__device__ __forceinline__ float xsgn(float f, unsigned m) {
    return __int_as_float(__float_as_int(f) ^ (int)m);
}
template<int M>
__device__ __forceinline__ float shx(float v) {
    return __int_as_float(__builtin_amdgcn_ds_swizzle(__float_as_int(v), (M << 10) | 0x1F));
}

// ---- deferred-CNOT gate masks, FORWARD circuit (validated R1-R5) ----
constexpr bool selon(int l, int d) {
    return (l == 0) ? (d == 0) : (((d + l - 1) & (l - 1)) == (l - 1));
}
constexpr int lm_of(int l, int q) {
    int m = 0;
    for (int d = 0; q + d <= 7; ++d)
        if ((l & d) == d) { int qq = q + d; if (qq <= 3) m |= 1 << (3 - qq); }
    return m;
}
constexpr int rm_of(int l, int q) {
    int m = 0;
    for (int d = 0; q + d <= 7; ++d)
        if ((l & d) == d) { int qq = q + d; if (qq >= 4) m |= 1 << (7 - qq); }
    return m;
}
constexpr int slm_of(int l, int q) {
    int m = 0;
    for (int d = 0; d <= q; ++d)
        if (selon(l, d)) { int k = q - d; if (k <= 3) m |= 1 << (3 - k); }
    return m;
}
constexpr int srm_of(int l, int q) {
    int m = 0;
    for (int d = 0; d <= q; ++d)
        if (selon(l, d)) { int k = q - d; if (k >= 4) m |= 1 << (7 - k); }
    return m;
}

template<int LM, int RM, int SLM, int SRM>
__device__ __forceinline__ void apply_gate(float ar[16], float ai[16], int lane,
                                           const float4 g)  // u00r,u00i,u01r,u01i
{
    unsigned sm = 0;
    if constexpr (SLM != 0)
        sm = (unsigned)((__builtin_popcount(lane & SLM) & 1) << 31);
    const float c0r = g.x, c1i = g.w;
    const float c0i0 = xsgn(g.y, sm);
    const float c1r0 = xsgn(g.z, sm);
    const float c0i1 = xsgn(g.y, sm ^ 0x80000000u);
    const float c1r1 = xsgn(g.z, sm ^ 0x80000000u);

    if constexpr (RM == 0) {
        #pragma unroll
        for (int r = 0; r < 16; ++r) {
            const bool c1 = (__builtin_popcount(r & SRM) & 1) != 0;
            const float c0i = c1 ? c0i1 : c0i0;
            const float c1r = c1 ? c1r1 : c1r0;
            const float br = shx<LM>(ar[r]);
            const float bi = shx<LM>(ai[r]);
            const float nr = c0r*ar[r] - c0i*ai[r] + c1r*br - c1i*bi;
            const float ni = c0r*ai[r] + c0i*ar[r] + c1r*bi + c1i*br;
            ar[r] = nr; ai[r] = ni;
        }
    } else {
        #pragma unroll
        for (int r = 0; r < 16; ++r) {
            const int p = r ^ RM;
            if (p < r) continue;
            float br_r, bi_r, br_p, bi_p;
            if constexpr (LM != 0) {
                br_r = shx<LM>(ar[p]); bi_r = shx<LM>(ai[p]);
                br_p = shx<LM>(ar[r]); bi_p = shx<LM>(ai[r]);
            } else {
                br_r = ar[p]; bi_r = ai[p];
                br_p = ar[r]; bi_p = ai[r];
            }
            const bool cr = (__builtin_popcount(r & SRM) & 1) != 0;
            const bool cp = (__builtin_popcount(p & SRM) & 1) != 0;
            const float c0i_r = cr ? c0i1 : c0i0, c1r_r = cr ? c1r1 : c1r0;
            const float c0i_p = cp ? c0i1 : c0i0, c1r_p = cp ? c1r1 : c1r0;
            const float nr_r = c0r*ar[r] - c0i_r*ai[r] + c1r_r*br_r - c1i*bi_r;
            const float ni_r = c0r*ai[r] + c0i_r*ar[r] + c1r_r*bi_r + c1i*br_r;
            const float nr_p = c0r*ar[p] - c0i_p*ai[p] + c1r_p*br_p - c1i*bi_p;
            const float ni_p = c0r*ai[p] + c0i_p*ar[p] + c1r_p*bi_p + c1i*br_p;
            ar[r] = nr_r; ai[r] = ni_r;
            ar[p] = nr_p; ai[p] = ni_p;
        }
    }
}

#define GATE(L, Q) apply_gate<lm_of(L,Q), rm_of(L,Q), slm_of(L,Q), srm_of(L,Q)>( \
                       ar, ai, lane, gsh4[(L)*8+(Q)])
#define LAYER(L) GATE(L,0); GATE(L,1); GATE(L,2); GATE(L,3); \
                 GATE(L,4); GATE(L,5); GATE(L,6); GATE(L,7);

// ---- kernel 1: build circuit matrix (16 blocks x 256 thr; 16 basis/block) ----
__global__ __launch_bounds__(256) void build_w(const float* __restrict__ w,
                                               unsigned short* __restrict__ W)
{
    __shared__ float4 gsh4[NGATES];
    const int tid = threadIdx.x;
    if (tid < NGATES) {
        float hx = 0.5f * w[tid*3+0];
        float hy = 0.5f * w[tid*3+1];
        float hz = 0.5f * w[tid*3+2];
        float cx = cosf(hx), sx = sinf(hx);
        float cy = cosf(hy), sy = sinf(hy);
        float cz = cosf(hz), sz = sinf(hz);
        float m00r = cy*cx,  m00i =  sy*sx;
        float m01r = -sy*cx, m01i = -cy*sx;
        gsh4[tid] = make_float4(cz*m00r + sz*m00i,
                                cz*m00i - sz*m00r,
                                cz*m01r + sz*m01i,
                                cz*m01i - sz*m01r);
    }
    __syncthreads();

    const int lane = tid & 63;
    const int il   = lane & 15;
    const int j    = blockIdx.x * 16 + (tid >> 4);   // basis state (true index)

    float ar[16], ai[16];
    #pragma unroll
    for (int r = 0; r < 16; ++r) {
        ar[r] = (((j >> 4) == il) && ((j & 15) == r)) ? 1.f : 0.f;
        ai[r] = 0.f;
    }
    LAYER(0)
    LAYER(1)
    LAYER(2)
    LAYER(3)
    #pragma unroll
    for (int r = 0; r < 16; ++r) {
        const int i = (il << 4) | r;                 // stored amp index
        W[i * 256 + j]         = f2bf(ar[r]);
        W[(256 + i) * 256 + j] = f2bf(ai[r]);
    }
}

// ---- kernel 2: E x W^T GEMM + signed-square epilogue; M=32 per block ----
#define ELS 272   // El row stride in shorts (34 s8v) -> <=2-way LDS banks

__global__ __launch_bounds__(256, 2) void gemm_z(const float* __restrict__ x,
                                                 const unsigned short* __restrict__ W,
                                                 float* __restrict__ out, int B)
{
    __shared__ __align__(16) unsigned short El[32 * ELS];
    __shared__ float zbuf[4][32][8];

    const int tid = threadIdx.x;
    const int Mbase = blockIdx.x * 32;

    // ---- encode 32 samples into LDS (bf16) ----
    #pragma unroll
    for (int ss = 0; ss < 2; ++ss) {
        const int s  = (tid >> 4) + 16 * ss;
        const int tk = tid & 15;
        const float4* xp = (const float4*)(x + (size_t)(Mbase + s) * 8);
        float4 xa = xp[0], xb = xp[1];
        float xs8[8] = {xa.x, xa.y, xa.z, xa.w, xb.x, xb.y, xb.z, xb.w};
        float c[8], sn[8];
        #pragma unroll
        for (int q = 0; q < 8; ++q) __sincosf(0.5f * xs8[q], &sn[q], &c[q]);
        float base = ((tk & 8) ? sn[0] : c[0]) * ((tk & 4) ? sn[1] : c[1])
                   * ((tk & 2) ? sn[2] : c[2]) * ((tk & 1) ? sn[3] : c[3]);
        float P45[4] = {c[4]*c[5], c[4]*sn[5], sn[4]*c[5], sn[4]*sn[5]};
        float P67[4] = {c[6]*c[7], c[6]*sn[7], sn[6]*c[7], sn[6]*sn[7]};
        unsigned short* dst = &El[s * ELS + tk * 16];
        #pragma unroll
        for (int v = 0; v < 16; ++v)
            dst[v] = f2bf(base * P45[v >> 2] * P67[v & 3]);
    }
    __syncthreads();

    const int lane = tid & 63;
    const int g    = tid >> 6;          // wave id = col-group (stored i bits 7:6)
    const int col  = lane & 15;
    const int quad = lane >> 4;
    const int nbase = g * 64;

    f4v accR[2][4], accI[2][4];         // [mtile][nt]
    #pragma unroll
    for (int mt = 0; mt < 2; ++mt)
        #pragma unroll
        for (int nt = 0; nt < 4; ++nt) {
            accR[mt][nt] = (f4v){0.f, 0.f, 0.f, 0.f};
            accI[mt][nt] = (f4v){0.f, 0.f, 0.f, 0.f};
        }

    const s8v* Wp = (const s8v*)W;
    const s8v* Ap = (const s8v*)El;     // row stride 34 (16B units)

    // 2-stage software-pipelined K-loop: fragments X (even ks), Y (odd ks)
    s8v a0X, a1X, bRX[4], bIX[4];
    s8v a0Y, a1Y, bRY[4], bIY[4];

    // preload ks=0 into X
    a0X = Ap[col * 34 + quad];
    a1X = Ap[(16 + col) * 34 + quad];
    #pragma unroll
    for (int nt = 0; nt < 4; ++nt) {
        const int nR = nbase + nt * 16 + col;
        bRX[nt] = Wp[nR * 32 + quad];
        bIX[nt] = Wp[(nR + 256) * 32 + quad];
    }

    #pragma unroll 1
    for (int ks = 0; ks < 8; ks += 2) {
        // prefetch ks+1 into Y
        a0Y = Ap[col * 34 + (ks + 1) * 4 + quad];
        a1Y = Ap[(16 + col) * 34 + (ks + 1) * 4 + quad];
        #pragma unroll
        for (int nt = 0; nt < 4; ++nt) {
            const int nR = nbase + nt * 16 + col;
            bRY[nt] = Wp[nR * 32 + (ks + 1) * 4 + quad];
            bIY[nt] = Wp[(nR + 256) * 32 + (ks + 1) * 4 + quad];
        }
        // MFMA with X (ks)
        #pragma unroll
        for (int nt = 0; nt < 4; ++nt) {
            accR[0][nt] = __builtin_amdgcn_mfma_f32_16x16x32_bf16(a0X, bRX[nt], accR[0][nt], 0, 0, 0);
            accR[1][nt] = __builtin_amdgcn_mfma_f32_16x16x32_bf16(a1X, bRX[nt], accR[1][nt], 0, 0, 0);
            accI[0][nt] = __builtin_amdgcn_mfma_f32_16x16x32_bf16(a0X, bIX[nt], accI[0][nt], 0, 0, 0);
            accI[1][nt] = __builtin_amdgcn_mfma_f32_16x16x32_bf16(a1X, bIX[nt], accI[1][nt], 0, 0, 0);
        }
        // prefetch ks+2 into X
        if (ks + 2 < 8) {
            a0X = Ap[col * 34 + (ks + 2) * 4 + quad];
            a1X = Ap[(16 + col) * 34 + (ks + 2) * 4 + quad];
            #pragma unroll
            for (int nt = 0; nt < 4; ++nt) {
                const int nR = nbase + nt * 16 + col;
                bRX[nt] = Wp[nR * 32 + (ks + 2) * 4 + quad];
                bIX[nt] = Wp[(nR + 256) * 32 + (ks + 2) * 4 + quad];
            }
        }
        // MFMA with Y (ks+1)
        #pragma unroll
        for (int nt = 0; nt < 4; ++nt) {
            accR[0][nt] = __builtin_amdgcn_mfma_f32_16x16x32_bf16(a0Y, bRY[nt], accR[0][nt], 0, 0, 0);
            accR[1][nt] = __builtin_amdgcn_mfma_f32_16x16x32_bf16(a1Y, bRY[nt], accR[1][nt], 0, 0, 0);
            accI[0][nt] = __builtin_amdgcn_mfma_f32_16x16x32_bf16(a0Y, bIY[nt], accI[0][nt], 0, 0, 0);
            accI[1][nt] = __builtin_amdgcn_mfma_f32_16x16x32_bf16(a1Y, bIY[nt], accI[1][nt], 0, 0, 0);
        }
    }

    // ---- epilogue (stored-index signs, validated R4/R5) ----
    const unsigned b1 = (unsigned)(col & 1) << 31;
    const unsigned b2 = (unsigned)(col & 2) << 30;
    const unsigned b4 = (unsigned)(col & 4) << 29;
    const unsigned b8 = (unsigned)(col & 8) << 28;
    const unsigned gm1 = (unsigned)(g & 2) << 30;
    const unsigned gm0 = (unsigned)(g & 1) << 31;

    #pragma unroll
    for (int mt = 0; mt < 2; ++mt) {
        float S0[4], S1[4], S2[4];
        #pragma unroll
        for (int reg = 0; reg < 4; ++reg) {
            float p0 = accR[mt][0][reg]*accR[mt][0][reg] + accI[mt][0][reg]*accI[mt][0][reg];
            float p1 = accR[mt][1][reg]*accR[mt][1][reg] + accI[mt][1][reg]*accI[mt][1][reg];
            float p2 = accR[mt][2][reg]*accR[mt][2][reg] + accI[mt][2][reg]*accI[mt][2][reg];
            float p3 = accR[mt][3][reg]*accR[mt][3][reg] + accI[mt][3][reg]*accI[mt][3][reg];
            S0[reg] = (p0 + p1) + (p2 + p3);
            S1[reg] = (p0 + p1) - (p2 + p3);   // q2 sign: nt bit1
            S2[reg] = (p0 - p1) + (p2 - p3);   // q3 sign: nt bit0
        }
        #pragma unroll
        for (int reg = 0; reg < 4; ++reg) {
            float v = S0[reg];
            { float t = shx<1>(v); v = t + xsgn(v, b1); }
            { float t = shx<2>(v); v = t + xsgn(v, b2); }
            { float t = shx<4>(v); v = t + xsgn(v, b4); }
            { float t = shx<8>(v); v = t + xsgn(v, b8); }
            S0[reg] = v;
            float u = S1[reg];
            { float t = shx<1>(u); u = t + xsgn(u, b1); }
            { float t = shx<2>(u); u = t + xsgn(u, b2); }
            { float t = shx<4>(u); u = t + xsgn(u, b4); }
            { float t = shx<8>(u); u = t + xsgn(u, b8); }
            S1[reg] = u;
            float t2 = S2[reg];
            { float t = shx<1>(t2); t2 = t + xsgn(t2, b1); }
            { float t = shx<2>(t2); t2 = t + xsgn(t2, b2); }
            { float t = shx<4>(t2); t2 = t + xsgn(t2, b4); }
            { float t = shx<8>(t2); t2 = t + xsgn(t2, b8); }
            S2[reg] = t2;
        }
        #pragma unroll
        for (int reg = 0; reg < 4; ++reg) {
            const int row = mt * 16 + quad * 4 + reg;
            if (col == 0) {
                zbuf[g][row][0] = xsgn(S0[reg], gm1);
                zbuf[g][row][1] = xsgn(S0[reg], gm0);
                zbuf[g][row][2] = S1[reg];
                zbuf[g][row][3] = S2[reg];
            } else if (col == 8) {
                zbuf[g][row][4] = xsgn(S0[reg], gm1);
            } else if (col == 4) {
                zbuf[g][row][5] = xsgn(S0[reg], gm0);
            } else if (col == 2) {
                zbuf[g][row][6] = S1[reg];
            } else if (col == 1) {
                zbuf[g][row][7] = S2[reg];
            }
        }
    }
    __syncthreads();

    {
        const int row = tid >> 3, q = tid & 7;
        out[(size_t)(Mbase + row) * 8 + q] = (zbuf[0][row][q] + zbuf[1][row][q])
                                           + (zbuf[2][row][q] + zbuf[3][row][q]);
    }
}

extern "C" void kernel_launch(void* const* d_in, const int* in_sizes, int n_in,
                              void* d_out, int out_size, void* d_ws, size_t ws_size,
                              hipStream_t stream) {
    const float* x = (const float*)d_in[0];
    const float* w = (const float*)d_in[1];
    float* out = (float*)d_out;
    unsigned short* W = (unsigned short*)d_ws;   // 512 x 256 bf16 = 256 KB
    const int B = in_sizes[0] / 8;               // 16384 samples
    build_w<<<16, 256, 0, stream>>>(w, W);
    gemm_z<<<B / 32, 256, 0, stream>>>(x, W, out, B);
}

// Round 8
// 79.815 us; speedup vs baseline: 1.2773x; 1.1243x over previous
//
#include <hip/hip_runtime.h>

// Phase 1 (build_w): one basis state per wave64 (256 blocks x 64 thr), using
// the R1-VALIDATED 4-amps/lane deferred-CNOT layout+masks: amp i = (lane<<2)|jj,
// qubit q <-> amp bit 7-q (q<=5 -> lane bit 5-q, q6/q7 -> jj bits 1/0).
// Output W (bf16) [n][k]: n=0..255 Re(amp i), n=256..511 Im; k = basis j.
// Phase 2 (gemm_z): byte-identical to R7 (passed): E x W^T MFMA 16x16x32,
// M=32/block, 2-stage pipelined K-loop, stored-space sign epilogue.

#define NGATES 32
typedef short s8v __attribute__((ext_vector_type(8)));   // 8 bf16 = 16 B
typedef float f4v __attribute__((ext_vector_type(4)));

__device__ __forceinline__ unsigned short f2bf(float f) {
    unsigned u = __float_as_uint(f);
    u += 0x7FFFu + ((u >> 16) & 1u);
    return (unsigned short)(u >> 16);
}
__device__ __forceinline__ float xsgn(float f, unsigned m) {
    return __int_as_float(__float_as_int(f) ^ (int)m);
}
template<int M>
__device__ __forceinline__ float shx(float v) {
    if constexpr (M == 0) {
        return v;
    } else if constexpr (M < 32) {
        return __int_as_float(__builtin_amdgcn_ds_swizzle(__float_as_int(v), (M << 10) | 0x1F));
    } else {
        return __shfl_xor(v, M, 64);
    }
}

// ---- R1-validated deferred-CNOT masks, 4-amps/lane layout ----
constexpr bool selon(int l, int d) {
    return (l == 0) ? (d == 0) : (((d + l - 1) & (l - 1)) == (l - 1));
}
constexpr int pairmask_lane(int l, int q) {
    int m = 0;
    for (int d = 0; q + d <= 7; ++d)
        if ((l & d) == d) { int qq = q + d; if (qq <= 5) m |= 1 << (5 - qq); }
    return m;
}
constexpr int pairmask_j(int l, int q) {
    int m = 0;
    for (int d = 0; q + d <= 7; ++d)
        if ((l & d) == d) { int qq = q + d; if (qq == 6) m |= 2; else if (qq == 7) m |= 1; }
    return m;
}
constexpr int selmask_lane(int l, int q) {
    int m = 0;
    for (int d = 0; d <= q; ++d)
        if (selon(l, d)) { int k = q - d; if (k <= 5) m |= 1 << (5 - k); }
    return m;
}
constexpr int selmask_j(int l, int q) {
    int m = 0;
    for (int d = 0; d <= q; ++d)
        if (selon(l, d)) { int k = q - d; if (k == 6) m |= 2; else if (k == 7) m |= 1; }
    return m;
}

// R1-validated apply_gate (4 amps/lane)
template<int LM, int JM, int SLM, int SJM>
__device__ __forceinline__ void apply_gate4(float ar[4], float ai[4], int lane,
                                            const float* __restrict__ g)
{
    const bool pl = (SLM == 0) ? false : (bool)(__builtin_popcount(lane & SLM) & 1);
    const float g0 = g[0], g1 = g[1], g2 = g[2], g3 = g[3];
    const float g4 = g[4], g5 = g[5], g6 = g[6], g7 = g[7];
    float nr[4], ni[4];
    #pragma unroll
    for (int j = 0; j < 4; ++j) {
        const bool flip = (__builtin_popcount(j & SJM) & 1) != 0;
        const bool s = pl != flip;
        const float c0r = s ? g6 : g0, c0i = s ? g7 : g1;   // diag coeff
        const float c1r = s ? g4 : g2, c1i = s ? g5 : g3;   // partner coeff
        const float br = shx<LM>(ar[j ^ JM]);
        const float bi = shx<LM>(ai[j ^ JM]);
        nr[j] = c0r*ar[j] - c0i*ai[j] + c1r*br - c1i*bi;
        ni[j] = c0r*ai[j] + c0i*ar[j] + c1r*bi + c1i*br;
    }
    #pragma unroll
    for (int j = 0; j < 4; ++j) { ar[j] = nr[j]; ai[j] = ni[j]; }
}

#define GATE4(L, Q) apply_gate4<pairmask_lane(L,Q), pairmask_j(L,Q), \
                                selmask_lane(L,Q), selmask_j(L,Q)>(ar, ai, lane, gsh[(L)*8+(Q)])
#define LAYER4(L) GATE4(L,0); GATE4(L,1); GATE4(L,2); GATE4(L,3); \
                  GATE4(L,4); GATE4(L,5); GATE4(L,6); GATE4(L,7);

// ---- kernel 1: one basis state per wave64; 256 blocks x 64 threads ----
__global__ __launch_bounds__(64) void build_w(const float* __restrict__ w,
                                              unsigned short* __restrict__ W)
{
    __shared__ float gsh[NGATES][8];  // u00r,u00i,u01r,u01i,u10r,u10i,u11r,u11i
    const int tid = threadIdx.x;
    if (tid < NGATES) {
        float hx = 0.5f * w[tid*3+0];
        float hy = 0.5f * w[tid*3+1];
        float hz = 0.5f * w[tid*3+2];
        float cx = cosf(hx), sx = sinf(hx);
        float cy = cosf(hy), sy = sinf(hy);
        float cz = cosf(hz), sz = sinf(hz);
        float m00r = cy*cx,  m00i =  sy*sx;
        float m01r = -sy*cx, m01i = -cy*sx;
        float m10r = sy*cx,  m10i = -cy*sx;
        float m11r = cy*cx,  m11i = -sy*sx;
        gsh[tid][0] = cz*m00r + sz*m00i;
        gsh[tid][1] = cz*m00i - sz*m00r;
        gsh[tid][2] = cz*m01r + sz*m01i;
        gsh[tid][3] = cz*m01i - sz*m01r;
        gsh[tid][4] = cz*m10r - sz*m10i;
        gsh[tid][5] = cz*m10i + sz*m10r;
        gsh[tid][6] = cz*m11r - sz*m11i;
        gsh[tid][7] = cz*m11i + sz*m11r;
    }
    __syncthreads();

    const int lane = tid;
    const int j    = blockIdx.x;        // basis state (true index)

    float ar[4], ai[4];
    #pragma unroll
    for (int jj = 0; jj < 4; ++jj) {
        ar[jj] = (lane == (j >> 2) && jj == (j & 3)) ? 1.f : 0.f;
        ai[jj] = 0.f;
    }
    LAYER4(0)
    LAYER4(1)
    LAYER4(2)
    LAYER4(3)

    #pragma unroll
    for (int jj = 0; jj < 4; ++jj) {
        const int i = (lane << 2) | jj;              // stored amp index
        W[i * 256 + j]         = f2bf(ar[jj]);
        W[(256 + i) * 256 + j] = f2bf(ai[jj]);
    }
}

// ---- kernel 2: byte-identical to R7 (passed) ----
#define ELS 272   // El row stride in shorts (34 s8v) -> <=2-way LDS banks

__global__ __launch_bounds__(256, 2) void gemm_z(const float* __restrict__ x,
                                                 const unsigned short* __restrict__ W,
                                                 float* __restrict__ out, int B)
{
    __shared__ __align__(16) unsigned short El[32 * ELS];
    __shared__ float zbuf[4][32][8];

    const int tid = threadIdx.x;
    const int Mbase = blockIdx.x * 32;

    #pragma unroll
    for (int ss = 0; ss < 2; ++ss) {
        const int s  = (tid >> 4) + 16 * ss;
        const int tk = tid & 15;
        const float4* xp = (const float4*)(x + (size_t)(Mbase + s) * 8);
        float4 xa = xp[0], xb = xp[1];
        float xs8[8] = {xa.x, xa.y, xa.z, xa.w, xb.x, xb.y, xb.z, xb.w};
        float c[8], sn[8];
        #pragma unroll
        for (int q = 0; q < 8; ++q) __sincosf(0.5f * xs8[q], &sn[q], &c[q]);
        float base = ((tk & 8) ? sn[0] : c[0]) * ((tk & 4) ? sn[1] : c[1])
                   * ((tk & 2) ? sn[2] : c[2]) * ((tk & 1) ? sn[3] : c[3]);
        float P45[4] = {c[4]*c[5], c[4]*sn[5], sn[4]*c[5], sn[4]*sn[5]};
        float P67[4] = {c[6]*c[7], c[6]*sn[7], sn[6]*c[7], sn[6]*sn[7]};
        unsigned short* dst = &El[s * ELS + tk * 16];
        #pragma unroll
        for (int v = 0; v < 16; ++v)
            dst[v] = f2bf(base * P45[v >> 2] * P67[v & 3]);
    }
    __syncthreads();

    const int lane = tid & 63;
    const int g    = tid >> 6;
    const int col  = lane & 15;
    const int quad = lane >> 4;
    const int nbase = g * 64;

    f4v accR[2][4], accI[2][4];
    #pragma unroll
    for (int mt = 0; mt < 2; ++mt)
        #pragma unroll
        for (int nt = 0; nt < 4; ++nt) {
            accR[mt][nt] = (f4v){0.f, 0.f, 0.f, 0.f};
            accI[mt][nt] = (f4v){0.f, 0.f, 0.f, 0.f};
        }

    const s8v* Wp = (const s8v*)W;
    const s8v* Ap = (const s8v*)El;

    s8v a0X, a1X, bRX[4], bIX[4];
    s8v a0Y, a1Y, bRY[4], bIY[4];

    a0X = Ap[col * 34 + quad];
    a1X = Ap[(16 + col) * 34 + quad];
    #pragma unroll
    for (int nt = 0; nt < 4; ++nt) {
        const int nR = nbase + nt * 16 + col;
        bRX[nt] = Wp[nR * 32 + quad];
        bIX[nt] = Wp[(nR + 256) * 32 + quad];
    }

    #pragma unroll 1
    for (int ks = 0; ks < 8; ks += 2) {
        a0Y = Ap[col * 34 + (ks + 1) * 4 + quad];
        a1Y = Ap[(16 + col) * 34 + (ks + 1) * 4 + quad];
        #pragma unroll
        for (int nt = 0; nt < 4; ++nt) {
            const int nR = nbase + nt * 16 + col;
            bRY[nt] = Wp[nR * 32 + (ks + 1) * 4 + quad];
            bIY[nt] = Wp[(nR + 256) * 32 + (ks + 1) * 4 + quad];
        }
        #pragma unroll
        for (int nt = 0; nt < 4; ++nt) {
            accR[0][nt] = __builtin_amdgcn_mfma_f32_16x16x32_bf16(a0X, bRX[nt], accR[0][nt], 0, 0, 0);
            accR[1][nt] = __builtin_amdgcn_mfma_f32_16x16x32_bf16(a1X, bRX[nt], accR[1][nt], 0, 0, 0);
            accI[0][nt] = __builtin_amdgcn_mfma_f32_16x16x32_bf16(a0X, bIX[nt], accI[0][nt], 0, 0, 0);
            accI[1][nt] = __builtin_amdgcn_mfma_f32_16x16x32_bf16(a1X, bIX[nt], accI[1][nt], 0, 0, 0);
        }
        if (ks + 2 < 8) {
            a0X = Ap[col * 34 + (ks + 2) * 4 + quad];
            a1X = Ap[(16 + col) * 34 + (ks + 2) * 4 + quad];
            #pragma unroll
            for (int nt = 0; nt < 4; ++nt) {
                const int nR = nbase + nt * 16 + col;
                bRX[nt] = Wp[nR * 32 + (ks + 2) * 4 + quad];
                bIX[nt] = Wp[(nR + 256) * 32 + (ks + 2) * 4 + quad];
            }
        }
        #pragma unroll
        for (int nt = 0; nt < 4; ++nt) {
            accR[0][nt] = __builtin_amdgcn_mfma_f32_16x16x32_bf16(a0Y, bRY[nt], accR[0][nt], 0, 0, 0);
            accR[1][nt] = __builtin_amdgcn_mfma_f32_16x16x32_bf16(a1Y, bRY[nt], accR[1][nt], 0, 0, 0);
            accI[0][nt] = __builtin_amdgcn_mfma_f32_16x16x32_bf16(a0Y, bIY[nt], accI[0][nt], 0, 0, 0);
            accI[1][nt] = __builtin_amdgcn_mfma_f32_16x16x32_bf16(a1Y, bIY[nt], accI[1][nt], 0, 0, 0);
        }
    }

    const unsigned b1 = (unsigned)(col & 1) << 31;
    const unsigned b2 = (unsigned)(col & 2) << 30;
    const unsigned b4 = (unsigned)(col & 4) << 29;
    const unsigned b8 = (unsigned)(col & 8) << 28;
    const unsigned gm1 = (unsigned)(g & 2) << 30;
    const unsigned gm0 = (unsigned)(g & 1) << 31;

    #pragma unroll
    for (int mt = 0; mt < 2; ++mt) {
        float S0[4], S1[4], S2[4];
        #pragma unroll
        for (int reg = 0; reg < 4; ++reg) {
            float p0 = accR[mt][0][reg]*accR[mt][0][reg] + accI[mt][0][reg]*accI[mt][0][reg];
            float p1 = accR[mt][1][reg]*accR[mt][1][reg] + accI[mt][1][reg]*accI[mt][1][reg];
            float p2 = accR[mt][2][reg]*accR[mt][2][reg] + accI[mt][2][reg]*accI[mt][2][reg];
            float p3 = accR[mt][3][reg]*accR[mt][3][reg] + accI[mt][3][reg]*accI[mt][3][reg];
            S0[reg] = (p0 + p1) + (p2 + p3);
            S1[reg] = (p0 + p1) - (p2 + p3);
            S2[reg] = (p0 - p1) + (p2 - p3);
        }
        #pragma unroll
        for (int reg = 0; reg < 4; ++reg) {
            float v = S0[reg];
            { float t = shx<1>(v); v = t + xsgn(v, b1); }
            { float t = shx<2>(v); v = t + xsgn(v, b2); }
            { float t = shx<4>(v); v = t + xsgn(v, b4); }
            { float t = shx<8>(v); v = t + xsgn(v, b8); }
            S0[reg] = v;
            float u = S1[reg];
            { float t = shx<1>(u); u = t + xsgn(u, b1); }
            { float t = shx<2>(u); u = t + xsgn(u, b2); }
            { float t = shx<4>(u); u = t + xsgn(u, b4); }
            { float t = shx<8>(u); u = t + xsgn(u, b8); }
            S1[reg] = u;
            float t2 = S2[reg];
            { float t = shx<1>(t2); t2 = t + xsgn(t2, b1); }
            { float t = shx<2>(t2); t2 = t + xsgn(t2, b2); }
            { float t = shx<4>(t2); t2 = t + xsgn(t2, b4); }
            { float t = shx<8>(t2); t2 = t + xsgn(t2, b8); }
            S2[reg] = t2;
        }
        #pragma unroll
        for (int reg = 0; reg < 4; ++reg) {
            const int row = mt * 16 + quad * 4 + reg;
            if (col == 0) {
                zbuf[g][row][0] = xsgn(S0[reg], gm1);
                zbuf[g][row][1] = xsgn(S0[reg], gm0);
                zbuf[g][row][2] = S1[reg];
                zbuf[g][row][3] = S2[reg];
            } else if (col == 8) {
                zbuf[g][row][4] = xsgn(S0[reg], gm1);
            } else if (col == 4) {
                zbuf[g][row][5] = xsgn(S0[reg], gm0);
            } else if (col == 2) {
                zbuf[g][row][6] = S1[reg];
            } else if (col == 1) {
                zbuf[g][row][7] = S2[reg];
            }
        }
    }
    __syncthreads();

    {
        const int row = tid >> 3, q = tid & 7;
        out[(size_t)(Mbase + row) * 8 + q] = (zbuf[0][row][q] + zbuf[1][row][q])
                                           + (zbuf[2][row][q] + zbuf[3][row][q]);
    }
}

extern "C" void kernel_launch(void* const* d_in, const int* in_sizes, int n_in,
                              void* d_out, int out_size, void* d_ws, size_t ws_size,
                              hipStream_t stream) {
    const float* x = (const float*)d_in[0];
    const float* w = (const float*)d_in[1];
    float* out = (float*)d_out;
    unsigned short* W = (unsigned short*)d_ws;   // 512 x 256 bf16 = 256 KB
    const int B = in_sizes[0] / 8;               // 16384 samples
    build_w<<<256, 64, 0, stream>>>(w, W);
    gemm_z<<<B / 32, 256, 0, stream>>>(x, W, out, B);
}